// Round 1
// baseline (123.075 us; speedup 1.0000x reference)
//
#include <hip/hip_runtime.h>
#include <math.h>

#define CCH 512      // channels
#define FH 76        // feature H
#define FW 128       // feature W
#define NP 256       // proposals
#define HID 200      // hidden width
#define NKC 16       // K-chunks for layer1 split-K (128 k each)
#define FM4 (FH * FW * (CCH / 4))      // 1,245,184 float4 in feature map
#define PG_THREADS (512 * 512)         // threads in poolgemm grid

// ---------------- Kernel 1: fused warm + ROI-pool + layer1 split-K ------
// R8 measured best (120.6us). The (row-tile, kc) split-K grid EXACTLY tiles
// the pooled feature matrix f[256][2048]: k-chunk kc covers bin kc>>2,
// channel block (kc&3)*128. Each block pools its own [8 proposals x 128 ch]
// f-subtile into LDS and immediately GEMMs it against its W1 chunk —
// no inter-block dependency, no f global round-trip.
// Phase A warm: the harness restores inputs then poisons 268MB of ws
// (cycles all of L2+L3), so every input is HBM-cold at kernel start;
// streaming fm+W1 coalesced pulls them into cache so the scattered pool
// reads and strided W1 reads hit ~200cyc instead of cold-HBM ~900cyc.
// R10: warm now also covers W2/W3/W4/b1..b4 (~176KB) so head_kernel's
// layer-2/head weight streams are L3-hits instead of cold HBM — the only
// input Phase A previously left cold. Costs +0.8% bytes on a BW-bound
// phase; removes cold-miss latency from head's serial chain.
// MEASURED LESSONS (do not revisit):
//  - R5: separate warm dispatch costs more than its ordering gain (+1.8us).
//  - R6: software grid barriers cost ~50us each at 256 blocks.
//  - R9: per-block __threadfence joins (last-finisher) force L2 writebacks
//    that re-cold the warm cache -> fused kernel 72us. Cross-block joins
//    must live at dispatch boundaries (~2us each).
__global__ __launch_bounds__(512) void poolgemm_kernel(
    const float4* __restrict__ fm4, const int* __restrict__ coords,
    const float* __restrict__ W1, const float* __restrict__ W2,
    const float* __restrict__ W3, const float* __restrict__ W4,
    const float* __restrict__ b1, const float* __restrict__ b2,
    const float* __restrict__ b3, const float* __restrict__ b4,
    float* __restrict__ part, float* __restrict__ scratch)
{
    __shared__ float4 sm[2][8][32];    // rslot x proposal x f4-group (8 KB)
    __shared__ float  fsub[8][128];    // pooled subtile (4 KB)
    __shared__ float  pc[2][8][HID];   // K-half partials (12.8 KB)

    const int t   = threadIdx.x;
    const int r0  = blockIdx.x * 8;          // 32 row-tiles
    const int kc  = blockIdx.y;              // 0..15
    const int bin = kc >> 2;
    const int cb  = (kc & 3) * 32;           // f4-group offset inside bin
    const int k0  = kc * 128;                // global k offset

    // ===== Phase A: cooperative cache warm (fm + all FC weights) =====
    {
        const int gtid = (blockIdx.y * 32 + blockIdx.x) * 512 + t;
        float wacc = -1e30f;
        #pragma unroll
        for (int i = 0; i < 5; ++i) {        // 5 x 262144 >= FM4
            const int idx = gtid + i * PG_THREADS;
            if (idx < FM4) {
                const float4 v = fm4[idx];
                wacc = fmaxf(wacc, fmaxf(fmaxf(v.x, v.y), fmaxf(v.z, v.w)));
            }
        }
        // Weight/bias warm: W1 102400 f4, W2 10000, W3 800, W4 250,
        // b1 50, b2 50, b3 4, b4 5 scalars. All < 262144 threads.
        float4 v = make_float4(-1e30f, -1e30f, -1e30f, -1e30f);
        if (gtid < 102400) {                 // W1: 2048*200/4 float4
            v = ((const float4*)W1)[gtid];
        } else if (gtid < 112400) {          // W2: 200*200/4
            v = ((const float4*)W2)[gtid - 102400];
        } else if (gtid < 113200) {          // W3: 200*16/4
            v = ((const float4*)W3)[gtid - 112400];
        } else if (gtid < 113450) {          // W4: 200*5/4
            v = ((const float4*)W4)[gtid - 113200];
        } else if (gtid < 113500) {          // b1: 200/4
            v = ((const float4*)b1)[gtid - 113450];
        } else if (gtid < 113550) {          // b2: 200/4
            v = ((const float4*)b2)[gtid - 113500];
        } else if (gtid < 113554) {          // b3: 16/4
            v = ((const float4*)b3)[gtid - 113550];
        } else if (gtid < 113559) {          // b4: 5 scalar floats
            v.x = b4[gtid - 113554];
        }
        wacc = fmaxf(wacc, fmaxf(fmaxf(v.x, v.y), fmaxf(v.z, v.w)));
        // DCE guard: data-dependent, never true for N(0,1)-scale inputs.
        if (wacc > 1e29f) scratch[0] = wacc;
    }

    // ===== Phase B: pool this block's [8 proposals x 128 ch] subtile =====
    {
        const int rslot = t >> 8;            // 0..1 (wave-uniform)
        const int nl    = (t >> 5) & 7;      // proposal within tile
        const int cg    = t & 31;            // f4-group within chunk
        const int n  = r0 + nl;
        const int c0 = coords[n*4+0], c1 = coords[n*4+1];
        const int c2 = coords[n*4+2], c3 = coords[n*4+3];
        const int sy = min(c0 >> 3, FH - 2);
        const int sx = min(c1 >> 3, FW - 2);
        const int h = max(((c2 + 7) >> 3) - sy, 2);
        const int w = max(((c3 + 7) >> 3) - sx, 2);
        const int by = bin >> 1, bx = bin & 1;
        // adaptive bin i covers [i*size/2, ((i+1)*size+1)/2)
        const int rs = by ? (h >> 1) : 0;
        const int re = by ? h : ((h + 1) >> 1);
        const int cs = bx ? (w >> 1) : 0;
        const int ce = bx ? w : ((w + 1) >> 1);
        const int nc = ce - cs;              // 1..12 cols
        float4 m = make_float4(-1e30f, -1e30f, -1e30f, -1e30f);
        for (int r = rs + rslot; r < re; r += 2) {
            const float4* row = fm4 +
                ((size_t)(sy + r) * FW + sx + cs) * (CCH/4) + cb + cg;
            #pragma unroll 4
            for (int cc = 0; cc < nc; ++cc) {
                const float4 v = row[(size_t)cc * (CCH/4)];
                m.x = fmaxf(m.x, v.x); m.y = fmaxf(m.y, v.y);
                m.z = fmaxf(m.z, v.z); m.w = fmaxf(m.w, v.w);
            }
        }
        sm[rslot][nl][cg] = m;
    }
    __syncthreads();
    if (t < 256) {
        const int nl = t >> 5, cg = t & 31;
        const float4 a = sm[0][nl][cg], b = sm[1][nl][cg];
        float4 o;
        o.x = fmaxf(a.x, b.x); o.y = fmaxf(a.y, b.y);
        o.z = fmaxf(a.z, b.z); o.w = fmaxf(a.w, b.w);
        *((float4*)&fsub[nl][cg * 4]) = o;   // 16B-aligned LDS store
    }
    __syncthreads();

    // ===== Phase C: GEMM chunk — part[kc][r0+r][j] over 128 k =====
    {
        const int half = t >> 8;             // K-half 0..1 (wave-uniform)
        const int j    = t & 255;
        if (j < HID) {
            float acc[8];
            #pragma unroll
            for (int r = 0; r < 8; ++r) acc[r] = 0.0f;
            const int kk0 = half * 64;
            const float* wp = W1 + (size_t)(k0 + kk0) * HID + j;  // coalesced in j
            #pragma unroll 8
            for (int kk = 0; kk < 64; ++kk) {
                const float wv = wp[(size_t)kk * HID];
                #pragma unroll
                for (int r = 0; r < 8; ++r)
                    acc[r] += fsub[r][kk0 + kk] * wv;   // LDS broadcast
            }
            #pragma unroll
            for (int r = 0; r < 8; ++r) pc[half][r][j] = acc[r];
        }
    }
    __syncthreads();
    if (t < HID) {
        float* pp = part + ((size_t)kc * NP + r0) * HID + t;
        #pragma unroll
        for (int r = 0; r < 8; ++r)
            pp[(size_t)r * HID] = pc[0][r][t] + pc[1][r][t];
    }
}

// ---------------- Kernel 2: reduce + layer2 + heads + postprocess --------
// One block (512 threads) per proposal; layer2 and heads are split over
// 2 K-halves (kc = t>>8, wave-uniform) to halve the serial load chains.
__global__ __launch_bounds__(512) void head_kernel(
    const float* __restrict__ part,
    const float* __restrict__ b1, const float* __restrict__ W2,
    const float* __restrict__ b2, const float* __restrict__ W3,
    const float* __restrict__ b3, const float* __restrict__ W4,
    const float* __restrict__ b4, const int* __restrict__ coords,
    float* __restrict__ out)
{
    __shared__ float h1s[HID];
    __shared__ float h2s[HID];
    __shared__ float p2[2][HID];
    __shared__ float hdp[2][21];
    __shared__ float hd[21];     // 16 reg + 5 cls
    const int n = blockIdx.x;
    const int t = threadIdx.x;
    const int kc = t >> 8;       // 0..1, wave-uniform
    const int j  = t & 255;
    if (t < HID) {
        float a = b1[t];
        #pragma unroll
        for (int c = 0; c < NKC; ++c)
            a += part[((size_t)c * NP + n) * HID + t];
        h1s[t] = fmaxf(a, 0.0f);
    }
    __syncthreads();
    if (j < HID) {
        const int k0 = kc * 100;
        float acc = 0.0f;
        #pragma unroll 10
        for (int k = 0; k < 100; ++k)
            acc += h1s[k0 + k] * W2[(k0 + k) * HID + j];
        p2[kc][j] = acc;
    }
    __syncthreads();
    if (t < HID) h2s[t] = fmaxf(p2[0][t] + p2[1][t] + b2[t], 0.0f);
    __syncthreads();
    if (j < 21) {
        const int k0 = kc * 100;
        float acc = 0.0f;
        if (j < 16) {
            #pragma unroll 5
            for (int k = 0; k < 100; ++k)
                acc += h2s[k0 + k] * W3[(k0 + k) * 16 + j];
        } else {
            const int ci = j - 16;
            #pragma unroll 5
            for (int k = 0; k < 100; ++k)
                acc += h2s[k0 + k] * W4[(k0 + k) * 5 + ci];
        }
        hdp[kc][j] = acc;
    }
    __syncthreads();
    if (t < 21)
        hd[t] = hdp[0][t] + hdp[1][t] + (t < 16 ? b3[t] : b4[t - 16]);
    __syncthreads();
    if (t == 0) {
        const float cv0 = hd[16], cv1 = hd[17], cv2 = hd[18],
                    cv3 = hd[19], cv4 = hd[20];
        // jnp.argmax: first occurrence of max -> strict '>'
        int cls = 0; float best = cv0;
        if (cv1 > best) { best = cv1; cls = 1; }
        if (cv2 > best) { best = cv2; cls = 2; }
        if (cv3 > best) { best = cv3; cls = 3; }
        if (cv4 > best) { best = cv4; cls = 4; }
        const float e0 = expf(cv0 - best), e1 = expf(cv1 - best),
                    e2 = expf(cv2 - best), e3 = expf(cv3 - best),
                    e4 = expf(cv4 - best);
        const float s = e0 + e1 + e2 + e3 + e4;
        const float score = fmaxf(fmaxf(e1, e2), fmaxf(e3, e4)) / s;
        const int ri = max(cls - 1, 0);
        const float rg0 = hd[ri*4+0], rg1 = hd[ri*4+1],
                    rg2 = hd[ri*4+2], rg3 = hd[ri*4+3];
        const float y0 = (float)coords[n*4+0], x0 = (float)coords[n*4+1];
        const float y1 = (float)coords[n*4+2], x1 = (float)coords[n*4+3];
        const float ph = y1 - y0, pw = x1 - x0;
        const float py = y0 + 0.5f * ph, px = x0 + 0.5f * pw;
        const float oy = ph * rg0 + py;
        const float ox = pw * rg1 + px;
        const float oh = ph * fminf(fmaxf(expf(rg2), 0.001f), 20.0f);
        const float ow = pw * fminf(fmaxf(expf(rg3), 0.001f), 20.0f);
        out[n*4+0] = oy; out[n*4+1] = ox; out[n*4+2] = oh; out[n*4+3] = ow;
        out[NP*4 + n] = score;                       // scores block
        out[NP*5 + n] = (cls != 0) ? 1.0f : 0.0f;    // mask block (bool as fp32)
    }
}

extern "C" void kernel_launch(void* const* d_in, const int* in_sizes, int n_in,
                              void* d_out, int out_size, void* d_ws, size_t ws_size,
                              hipStream_t stream) {
    const float* fm     = (const float*)d_in[0];   // [1,76,128,512]
    const int*   coords = (const int*)  d_in[1];   // [256,4]
    const float* W1 = (const float*)d_in[2];       // [2048,200]
    const float* b1 = (const float*)d_in[3];
    const float* W2 = (const float*)d_in[4];       // [200,200]
    const float* b2 = (const float*)d_in[5];
    const float* W3 = (const float*)d_in[6];       // [200,16]
    const float* b3 = (const float*)d_in[7];
    const float* W4 = (const float*)d_in[8];       // [200,5]
    const float* b4 = (const float*)d_in[9];
    float* out = (float*)d_out;                    // 1024 boxes + 256 scores + 256 mask

    float* part    = (float*)d_ws;                 // [16, 256, 200]
    float* scratch = part + (size_t)NKC * NP * HID;

    poolgemm_kernel<<<dim3(32, NKC), 512, 0, stream>>>(
        (const float4*)fm, coords, W1, W2, W3, W4, b1, b2, b3, b4,
        part, scratch);
    head_kernel<<<NP, 512, 0, stream>>>(part, b1, W2, b2, W3, b3, W4, b4,
                                        coords, out);
}